// Round 11
// baseline (249.000 us; speedup 1.0000x reference)
//
#include <hip/hip_runtime.h>
#include <hip/hip_bf16.h>

// PointPillarScatter, fused single-pass gather: out[b, c, y, x] = feat[p, c]
// for valid pillar p at (b, x, y); zeros elsewhere. Output [B, C, ny, nx] f32.
//
// cellmap[B*G] (d_ws) maps cell -> pillar (-1 empty). One dense pass writes
// every output element exactly once with NONTEMPORAL float4 stores (the
// output is write-once, never re-read: bypass L2 so 219 MB of dirty lines
// don't thrash it). Consecutive threads cover consecutive cell quads ->
// each wave-instruction stores 1 KB contiguous per channel plane.
//
// NOTE: __builtin_nontemporal_store needs a NATIVE vector type; HIP's float4
// is a class -> use ext_vector_type(4).

typedef float f32x4 __attribute__((ext_vector_type(4)));
typedef int   i32x4 __attribute__((ext_vector_type(4)));

__global__ void pp_build_map(const int* __restrict__ coords,
                             const int* __restrict__ mask,
                             const int* __restrict__ p_B,
                             const int* __restrict__ p_nx,
                             const int* __restrict__ p_ny,
                             const int* __restrict__ p_nz,
                             int* __restrict__ cellmap, int P) {
    const int p = blockIdx.x * blockDim.x + threadIdx.x;
    if (p >= P) return;
    if (mask[p] <= 0) return;                      // invalid -> dropped
    const int nx = *p_nx, ny = *p_ny, nz = *p_nz, B = *p_B;
    const long long G = (long long)nx * ny * nz;
    const int b = coords[4 * p + 0];
    const int x = coords[4 * p + 1];
    const int y = coords[4 * p + 2];
    const int z = coords[4 * p + 3];
    const long long flat = (long long)b * G + (long long)x + (long long)y * nx + z;
    if (flat < 0 || flat >= (long long)B * G) return;   // mode='drop'
    cellmap[flat] = p;
}

// gridDim.x covers BG/4 cell quads; gridDim.y = CS slices of CL channels.
__global__ void pp_dense_all(const float* __restrict__ feat,
                             const int* __restrict__ cellmap,
                             const int* __restrict__ p_nx,
                             const int* __restrict__ p_ny,
                             const int* __restrict__ p_nz,
                             float* __restrict__ out,
                             int BG, int C, int CL) {
    const int q = blockIdx.x * blockDim.x + threadIdx.x;
    const int u0 = q << 2;                       // first cell of the quad
    if (u0 >= BG) return;
    const int c_begin = blockIdx.y * CL;
    const f32x4 z4 = {0.f, 0.f, 0.f, 0.f};

    const int nz = *p_nz;
    if (nz != 1) {
        // Zero-fill only (exact once-coverage, out as [C][BG]); the general
        // scatter kernel completes the pillar writes afterwards.
        float* o = out + (size_t)c_begin * BG + u0;
        for (int k = 0; k < CL; ++k, o += BG)
            __builtin_nontemporal_store(z4, (f32x4*)o);
        return;
    }

    const int G = (*p_nx) * (*p_ny);

    if ((G & 3) != 0) {
        // Rare shape: a quad may span batches -> per-cell path (correct, slow).
        for (int i = 0; i < 4; ++i) {
            const int u = u0 + i;
            if (u >= BG) return;
            int b = 0, base = G;
            while (u >= base) { base += G; ++b; }
            const int cell = u - (base - G);
            const int pm = cellmap[u];
            const float* r = feat + (size_t)pm * C + c_begin;
            float* o = out + ((size_t)b * C + c_begin) * (size_t)G + cell;
            for (int c = 0; c < CL; ++c, o += G)
                __builtin_nontemporal_store(pm >= 0 ? r[c] : 0.0f, o);
        }
        return;
    }

    // b = u0 / G via short ladder (B small); quad stays in one batch (G%4==0).
    int b = 0, base = G;
    while (u0 >= base) { base += G; ++b; }
    const int cell0 = u0 - (base - G);

    const i32x4 pm = *(const i32x4*)(cellmap + u0);        // 16B, u0 % 4 == 0
    const float* r0 = feat + (size_t)pm.x * C + c_begin;
    const float* r1 = feat + (size_t)pm.y * C + c_begin;
    const float* r2 = feat + (size_t)pm.z * C + c_begin;
    const float* r3 = feat + (size_t)pm.w * C + c_begin;

    float* o = out + ((size_t)b * C + c_begin) * (size_t)G + cell0;

    #pragma unroll 4
    for (int c = 0; c < CL; c += 4) {
        f32x4 a = z4, d = z4, e = z4, f = z4;              // rows, ch c..c+3
        if (pm.x >= 0) a = *(const f32x4*)(r0 + c);
        if (pm.y >= 0) d = *(const f32x4*)(r1 + c);
        if (pm.z >= 0) e = *(const f32x4*)(r2 + c);
        if (pm.w >= 0) f = *(const f32x4*)(r3 + c);
        // 4x4 register transpose; one 1 KB/wave contiguous NT store per plane.
        f32x4 t0 = {a.x, d.x, e.x, f.x};
        f32x4 t1 = {a.y, d.y, e.y, f.y};
        f32x4 t2 = {a.z, d.z, e.z, f.z};
        f32x4 t3 = {a.w, d.w, e.w, f.w};
        __builtin_nontemporal_store(t0, (f32x4*)o); o += G;
        __builtin_nontemporal_store(t1, (f32x4*)o); o += G;
        __builtin_nontemporal_store(t2, (f32x4*)o); o += G;
        __builtin_nontemporal_store(t3, (f32x4*)o); o += G;
    }
}

// General-layout completion (acts only when nz != 1 on the fused path).
__global__ void pp_scatter_general(const float* __restrict__ feat,
                                   const int* __restrict__ coords,
                                   const int* __restrict__ mask,
                                   const int* __restrict__ p_B,
                                   const int* __restrict__ p_nx,
                                   const int* __restrict__ p_ny,
                                   const int* __restrict__ p_nz,
                                   float* __restrict__ out,
                                   int P, int C, int only_general) {
    const int p = blockIdx.x * blockDim.x + threadIdx.x;
    if (p >= P) return;
    const int nz = *p_nz;
    if (only_general && nz == 1) return;
    if (mask[p] <= 0) return;
    const int nx = *p_nx, ny = *p_ny, B = *p_B;
    const int b = coords[4 * p + 0];
    const int x = coords[4 * p + 1];
    const int y = coords[4 * p + 2];
    const int z = coords[4 * p + 3];
    const long long G = (long long)nx * ny * nz;
    const long long flat = (long long)b * G + (long long)x + (long long)y * nx + z;
    if (flat < 0 || flat >= (long long)B * G) return;
    for (int c = 0; c < C; ++c) {
        const float v = feat[(size_t)p * C + c];
        if (nz == 1) {
            out[((size_t)(b * C + c) * ny + y) * nx + x] = v;
        } else {
            const long long lin = flat * C + c;
            const long long Cnz = (long long)C * nz;
            const long long c2 = lin % Cnz;
            long long t = lin / Cnz;
            const long long x2 = t % nx;  t /= nx;
            const long long y2 = t % ny;
            const long long b2 = t / ny;
            out[((b2 * Cnz + c2) * ny + y2) * nx + x2] = v;
        }
    }
}

extern "C" void kernel_launch(void* const* d_in, const int* in_sizes, int n_in,
                              void* d_out, int out_size, void* d_ws, size_t ws_size,
                              hipStream_t stream) {
    const float* feat   = (const float*)d_in[0];
    const int*   coords = (const int*)d_in[1];
    const int*   mask   = (const int*)d_in[2];
    const int*   p_B    = (const int*)d_in[3];
    const int*   p_nx   = (const int*)d_in[4];
    const int*   p_ny   = (const int*)d_in[5];
    const int*   p_nz   = (const int*)d_in[6];

    const int P = in_sizes[1] / 4;          // coords [P, 4]
    const int C = in_sizes[0] / P;          // features [P, C]
    const int BG = out_size / C;            // B*G
    float* out = (float*)d_out;

    const int block = 256;
    const bool fused_ok = (ws_size >= (size_t)BG * sizeof(int)) &&
                          (BG % 4 == 0) && (C % 4 == 0);

    if (fused_ok) {
        int* cellmap = (int*)d_ws;
        (void)hipMemsetAsync(cellmap, 0xFF, (size_t)BG * sizeof(int), stream); // -1
        pp_build_map<<<(P + block - 1) / block, block, 0, stream>>>(
            coords, mask, p_B, p_nx, p_ny, p_nz, cellmap, P);

        const int CS = (C % 8 == 0) ? 2 : 1;     // channel slices
        const int CL = C / CS;
        dim3 grid((BG / 4 + block - 1) / block, CS, 1);
        pp_dense_all<<<grid, block, 0, stream>>>(
            feat, cellmap, p_nx, p_ny, p_nz, out, BG, C, CL);

        // no-op unless nz != 1
        pp_scatter_general<<<(P + block - 1) / block, block, 0, stream>>>(
            feat, coords, mask, p_B, p_nx, p_ny, p_nz, out, P, C, 1);
    } else {
        (void)hipMemsetAsync(out, 0, (size_t)out_size * sizeof(float), stream);
        pp_scatter_general<<<(P + block - 1) / block, block, 0, stream>>>(
            feat, coords, mask, p_B, p_nx, p_ny, p_nz, out, P, C, 0);
    }
}